// Round 8
// baseline (114.584 us; speedup 1.0000x reference)
//
#include <hip/hip_runtime.h>

#define D_    2560
#define NH_   8
#define NKV_  4
#define HD_   256
#define FFN_  10240
#define QD_   2048
#define CTX_  4096
#define EPSF  1e-6f
#define SCH   128   // score chunks
#define WCH   64    // wv chunks

typedef float f4 __attribute__((ext_vector_type(4)));

__device__ __forceinline__ float wave_red_sum(float v) {
#pragma unroll
    for (int o = 32; o > 0; o >>= 1) v += __shfl_down(v, o, 64);
    return v;
}

__device__ __forceinline__ float block_red_sum(float v) {
    __shared__ float s[4];
    __shared__ float tot;
    int lane = threadIdx.x & 63, w = threadIdx.x >> 6;
    v = wave_red_sum(v);
    if (lane == 0) s[w] = v;
    __syncthreads();
    if (threadIdx.x == 0) tot = s[0] + s[1] + s[2] + s[3];
    __syncthreads();
    return tot;
}

__device__ __forceinline__ float block_red_max(float v) {
    __shared__ float s[4];
    __shared__ float tot;
    int lane = threadIdx.x & 63, w = threadIdx.x >> 6;
#pragma unroll
    for (int o = 32; o > 0; o >>= 1) v = fmaxf(v, __shfl_down(v, o, 64));
    if (lane == 0) s[w] = v;
    __syncthreads();
    if (threadIdx.x == 0) tot = fmaxf(fmaxf(s[0], s[1]), fmaxf(s[2], s[3]));
    __syncthreads();
    return tot;
}

// ---- persistent task-stream GEMV: task = row of CPL chunks, weight
// address linear in task id, CPL nt loads back-to-back, x from L1 (loop-
// invariant, hoistable to VGPRs).  No LDS, no barriers. ----
template <int CPL>
__global__ __launch_bounds__(256) void k_gemv_p(const float* __restrict__ W,
                                                const float* __restrict__ x,
                                                float* __restrict__ y, int ntask) {
    int lane = threadIdx.x & 63;
    int gw = (blockIdx.x * 256 + threadIdx.x) >> 6;
    int nw = (gridDim.x * 256) >> 6;
    const f4* X = (const f4*)x;
    for (int t = gw; t < ntask; t += nw) {
        const f4* Wr = (const f4*)W + (size_t)t * (CPL * 64) + lane;
        f4 wv[CPL];
#pragma unroll
        for (int k = 0; k < CPL; k++) wv[k] = __builtin_nontemporal_load(Wr + k * 64);
        float acc = 0.f;
#pragma unroll
        for (int k = 0; k < CPL; k++) {
            f4 xx = X[k * 64 + lane];
            acc += wv[k].x * xx.x + wv[k].y * xx.y + wv[k].z * xx.z + wv[k].w * xx.w;
        }
        acc = wave_red_sum(acc);
        if (lane == 0) y[t] = acc;
    }
}

// ---- fused GeGLU task-stream: task = row; 20 nt loads (G then U). ----
__global__ __launch_bounds__(256) void k_geglu_p(const float* __restrict__ Wg,
                                                 const float* __restrict__ Wu,
                                                 const float* __restrict__ h,
                                                 float* __restrict__ gu) {
    int lane = threadIdx.x & 63;
    int gw = (blockIdx.x * 256 + threadIdx.x) >> 6;
    int nw = (gridDim.x * 256) >> 6;
    const f4* X = (const f4*)h;
    for (int t = gw; t < FFN_; t += nw) {
        const f4* G = (const f4*)Wg + (size_t)t * 640 + lane;
        const f4* U = (const f4*)Wu + (size_t)t * 640 + lane;
        f4 wg[10], wu[10];
#pragma unroll
        for (int k = 0; k < 10; k++) wg[k] = __builtin_nontemporal_load(G + k * 64);
#pragma unroll
        for (int k = 0; k < 10; k++) wu[k] = __builtin_nontemporal_load(U + k * 64);
        float ag = 0.f, au = 0.f;
#pragma unroll
        for (int k = 0; k < 10; k++) {
            f4 xx = X[k * 64 + lane];
            ag += wg[k].x * xx.x + wg[k].y * xx.y + wg[k].z * xx.z + wg[k].w * xx.w;
            au += wu[k].x * xx.x + wu[k].y * xx.y + wu[k].z * xx.z + wu[k].w * xx.w;
        }
#pragma unroll
        for (int o = 32; o > 0; o >>= 1) {
            ag += __shfl_down(ag, o, 64);
            au += __shfl_down(au, o, 64);
        }
        if (lane == 0) {
            float g = ag;
            float tt = tanhf(0.7978845608028654f * (g + 0.044715f * g * g * g));
            gu[t] = 0.5f * g * (1.f + tt) * au;
        }
    }
}

// ---- Wd task-stream: task = (row,seg), 10 nt loads, partial out.
// part[t], t = row*4+seg; weight address linear in t. ----
__global__ __launch_bounds__(256) void k_wd_p(const float* __restrict__ Wd,
                                              const float* __restrict__ gu,
                                              float* __restrict__ part) {
    int lane = threadIdx.x & 63;
    int gw = (blockIdx.x * 256 + threadIdx.x) >> 6;
    int nw = (gridDim.x * 256) >> 6;
    const f4* X = (const f4*)gu;
    for (int t = gw; t < D_ * 4; t += nw) {
        int seg = t & 3;
        const f4* Wr = (const f4*)Wd + (size_t)t * 640 + lane;
        f4 wv[10];
#pragma unroll
        for (int k = 0; k < 10; k++) wv[k] = __builtin_nontemporal_load(Wr + k * 64);
        const f4* xw = X + seg * 640 + lane;
        float acc = 0.f;
#pragma unroll
        for (int k = 0; k < 10; k++) {
            f4 xx = xw[k * 64];
            acc += wv[k].x * xx.x + wv[k].y * xx.y + wv[k].z * xx.z + wv[k].w * xx.w;
        }
        acc = wave_red_sum(acc);
        if (lane == 0) part[t] = acc;
    }
}

// out1 = (res?) res + rms(a)*(1+w1);  a[i] = sum_{s<slots} apart[i*slots+s]
// optionally out2 = rms(out1)*(1+w2).  one block, 256 threads.
__global__ void k_res_rms(const float* __restrict__ res,
                          const float* __restrict__ apart, int slots,
                          const float* __restrict__ w1, float* __restrict__ out1,
                          const float* __restrict__ w2, float* __restrict__ out2) {
    const int K = D_ / 256;
    int t = threadIdx.x;
    float va[K];
    float ss = 0.f;
#pragma unroll
    for (int k = 0; k < K; k++) {
        int i = t + k * 256;
        float v = 0.f;
        for (int s = 0; s < slots; s++) v += apart[(size_t)i * slots + s];
        va[k] = v;
        ss += v * v;
    }
    float tot = block_red_sum(ss);
    float rs = rsqrtf(tot / (float)D_ + EPSF);
    float vo[K];
    float ss2 = 0.f;
#pragma unroll
    for (int k = 0; k < K; k++) {
        int i = t + k * 256;
        float r = res ? res[i] : 0.f;
        vo[k] = r + va[k] * rs * (1.f + w1[i]);
        out1[i] = vo[k];
        ss2 += vo[k] * vo[k];
    }
    if (out2) {
        float tot2 = block_red_sum(ss2);
        float rs2 = rsqrtf(tot2 / (float)D_ + EPSF);
#pragma unroll
        for (int k = 0; k < K; k++) {
            int i = t + k * 256;
            out2[i] = vo[k] * rs2 * (1.f + w2[i]);
        }
    }
}

__global__ void k_qnorm_rope(const float* __restrict__ qraw,
                             const float* __restrict__ cosv,
                             const float* __restrict__ sinv,
                             float* __restrict__ qout) {
    __shared__ float qn[HD_];
    int h = blockIdx.x, d = threadIdx.x;
    float v = qraw[h * HD_ + d];
    float tot = block_red_sum(v * v);
    float rs = rsqrtf(tot / (float)HD_ + EPSF);
    float n = v * rs;
    qn[d] = n;
    __syncthreads();
    float rot = (d < HD_ / 2) ? -qn[d + HD_ / 2] : qn[d - HD_ / 2];
    qout[h * HD_ + d] = n * cosv[d] + rot * sinv[d];
}

// scores: grid=(NKV_, SCH), block=256.  8 rows/wave, loads before reduces.
__global__ __launch_bounds__(256) void k_scores(const float* __restrict__ Kc,
                                                const float* __restrict__ q,
                                                const float* __restrict__ mask,
                                                float* __restrict__ s) {
    int kvh = blockIdx.x, chunk = blockIdx.y;
    int lane = threadIdx.x & 63, w = threadIdx.x >> 6;
    int h0 = 2 * kvh, h1 = h0 + 1;
    const f4* q4 = (const f4*)q;
    f4 q0 = q4[h0 * 64 + lane];
    f4 q1 = q4[h1 * 64 + lane];
    int lbase = chunk * (CTX_ / SCH) + w * 8;
    const f4* Kb = (const f4*)(Kc + ((size_t)kvh * CTX_ + lbase) * HD_) + lane;
    f4 kk[8];
#pragma unroll
    for (int i = 0; i < 8; i++) kk[i] = Kb[i * 64];
    float d0[8], d1[8];
#pragma unroll
    for (int i = 0; i < 8; i++) {
        d0[i] = kk[i].x * q0.x + kk[i].y * q0.y + kk[i].z * q0.z + kk[i].w * q0.w;
        d1[i] = kk[i].x * q1.x + kk[i].y * q1.y + kk[i].z * q1.z + kk[i].w * q1.w;
    }
#pragma unroll
    for (int o = 32; o > 0; o >>= 1) {
#pragma unroll
        for (int i = 0; i < 8; i++) {
            d0[i] += __shfl_down(d0[i], o, 64);
            d1[i] += __shfl_down(d1[i], o, 64);
        }
    }
    if (lane == 0) {
#pragma unroll
        for (int i = 0; i < 8; i++) {
            int l = lbase + i;
            float m = mask[l];
            s[(size_t)h0 * CTX_ + l] = d0[i] + m;
            s[(size_t)h1 * CTX_ + l] = d1[i] + m;
        }
    }
}

__global__ void k_softmax(float* __restrict__ s) {
    int h = blockIdx.x, t = threadIdx.x;
    float* sh = s + (size_t)h * CTX_;
    float m = -1e30f;
    for (int l = t; l < CTX_; l += 256) m = fmaxf(m, sh[l]);
    m = block_red_max(m);
    float sum = 0.f;
    for (int l = t; l < CTX_; l += 256) {
        float e = expf(sh[l] - m);
        sh[l] = e;
        sum += e;
    }
    sum = block_red_sum(sum);
    float inv = 1.f / sum;
    for (int l = t; l < CTX_; l += 256) sh[l] *= inv;
}

// wv: grid=(NKV_, WCH), block=256 (thread = d).  64 rows/chunk, streaming.
__global__ __launch_bounds__(256) void k_wv(const float* __restrict__ V,
                                            const float* __restrict__ p,
                                            float* __restrict__ part) {
    int kvh = blockIdx.x, chunk = blockIdx.y, d = threadIdx.x;
    int h0 = 2 * kvh, h1 = h0 + 1;
    constexpr int R = CTX_ / WCH;   // 64 rows
    __shared__ float p0[R], p1[R];
    int l0 = chunk * R;
    if (d < R) p0[d] = p[(size_t)h0 * CTX_ + l0 + d];
    else if (d < 2 * R) p1[d - R] = p[(size_t)h1 * CTX_ + l0 + d - R];
    __syncthreads();
    const float* Vb = V + ((size_t)kvh * CTX_ + l0) * HD_;
    float a0 = 0.f, a1 = 0.f;
#pragma unroll 8
    for (int li = 0; li < R; li++) {
        float v = Vb[(size_t)li * HD_ + d];
        a0 += p0[li] * v;
        a1 += p1[li] * v;
    }
    part[((h0 * WCH) + chunk) * HD_ + d] = a0;
    part[((h1 * WCH) + chunk) * HD_ + d] = a1;
}

__global__ void k_reduce_a(const float* __restrict__ part, float* __restrict__ a) {
    int h = blockIdx.x, d = threadIdx.x;
    float s = 0.f;
#pragma unroll
    for (int c = 0; c < WCH; c++) s += part[((h * WCH) + c) * HD_ + d];
    a[h * HD_ + d] = s;
}

extern "C" void kernel_launch(void* const* d_in, const int* in_sizes, int n_in,
                              void* d_out, int out_size, void* d_ws, size_t ws_size,
                              hipStream_t stream) {
    const float* x     = (const float*)d_in[0];
    const float* cosv  = (const float*)d_in[1];
    const float* sinv  = (const float*)d_in[2];
    const float* mask  = (const float*)d_in[3];
    const float* cK    = (const float*)d_in[4];
    const float* cV    = (const float*)d_in[5];
    const float* w_in  = (const float*)d_in[7];
    const float* w_pa  = (const float*)d_in[8];
    const float* w_pf  = (const float*)d_in[9];
    const float* w_pff = (const float*)d_in[10];
    const float* Wq    = (const float*)d_in[11];
    const float* Wo    = (const float*)d_in[12];
    const float* Wg    = (const float*)d_in[13];
    const float* Wu    = (const float*)d_in[14];
    const float* Wd    = (const float*)d_in[15];

    float* ws    = (float*)d_ws;
    float* h     = ws;             // 2560
    float* qraw  = ws + 2560;      // 2048
    float* q     = ws + 4608;      // 2048
    float* sc    = ws + 6656;      // 32768
    float* pwv   = ws + 39424;     // 131072
    float* a     = ws + 170496;    // 2048
    float* ao    = ws + 172544;    // 2560
    float* x2    = ws + 175104;    // 2560
    float* h2    = ws + 177664;    // 2560
    float* gu    = ws + 180224;    // 10240
    float* partd = ws + 190464;    // 10240
    float* out   = (float*)d_out;

    // h = rmsnorm(x, w_in)
    k_res_rms<<<1, 256, 0, stream>>>(nullptr, x, 1, w_in, h, nullptr, nullptr);
    // qraw = h @ Wq.T   (2048 tasks, 512 blocks -> 1 task/wave)
    k_gemv_p<10><<<512, 256, 0, stream>>>(Wq, h, qraw, QD_);
    k_qnorm_rope<<<NH_, HD_, 0, stream>>>(qraw, cosv, sinv, q);
    // attention
    k_scores<<<dim3(NKV_, SCH), 256, 0, stream>>>(cK, q, mask, sc);
    k_softmax<<<NH_, 256, 0, stream>>>(sc);
    k_wv<<<dim3(NKV_, WCH), 256, 0, stream>>>(cV, sc, pwv);
    k_reduce_a<<<NH_, HD_, 0, stream>>>(pwv, a);
    // ao = a @ Wo.T   (2560 tasks, 640 blocks -> 1 task/wave)
    k_gemv_p<8><<<640, 256, 0, stream>>>(Wo, a, ao, D_);
    k_res_rms<<<1, 256, 0, stream>>>(x, ao, 1, w_pa, x2, w_pf, h2);
    // gu = gelu(h2@Wg.T) * (h2@Wu.T)  (10240 tasks, 512 blocks -> 5/wave)
    k_geglu_p<<<512, 256, 0, stream>>>(Wg, Wu, h2, gu);
    // ffn partials = gu @ Wd.T  (10240 tasks, 512 blocks -> 5/wave)
    k_wd_p<<<512, 256, 0, stream>>>(Wd, gu, partd);
    // out = x2 + rms(sum partd)*(1+w_pff)
    k_res_rms<<<1, 256, 0, stream>>>(x2, partd, 4, w_pff, out, nullptr, nullptr);
}

// Round 9
// 99.582 us; speedup vs baseline: 1.1507x; 1.1507x over previous
//
#include <hip/hip_runtime.h>

#define D_    2560
#define NH_   8
#define NKV_  4
#define HD_   256
#define FFN_  10240
#define QD_   2048
#define CTX_  4096
#define EPSF  1e-6f
#define ACH   64    // attention chunks per kv head (64 rows each)

typedef float f4 __attribute__((ext_vector_type(4)));

__device__ __forceinline__ float wave_red_sum(float v) {
#pragma unroll
    for (int o = 32; o > 0; o >>= 1) v += __shfl_down(v, o, 64);
    return v;
}

// butterfly: result in ALL lanes
__device__ __forceinline__ float wave_red_sum_b(float v) {
#pragma unroll
    for (int o = 32; o > 0; o >>= 1) v += __shfl_xor(v, o, 64);
    return v;
}

__device__ __forceinline__ float block_red_sum(float v) {
    __shared__ float s[4];
    __shared__ float tot;
    int lane = threadIdx.x & 63, w = threadIdx.x >> 6;
    v = wave_red_sum(v);
    if (lane == 0) s[w] = v;
    __syncthreads();
    if (threadIdx.x == 0) tot = s[0] + s[1] + s[2] + s[3];
    __syncthreads();
    return tot;
}

__device__ __forceinline__ float block_red_max(float v) {
    __shared__ float s[4];
    __shared__ float tot;
    int lane = threadIdx.x & 63, w = threadIdx.x >> 6;
#pragma unroll
    for (int o = 32; o > 0; o >>= 1) v = fmaxf(v, __shfl_down(v, o, 64));
    if (lane == 0) s[w] = v;
    __syncthreads();
    if (threadIdx.x == 0) tot = fmaxf(fmaxf(s[0], s[1]), fmaxf(s[2], s[3]));
    __syncthreads();
    return tot;
}

// ---- probe-shaped GEMV: 1 row per wave, CPL back-to-back nt loads,
// x via plain (cached) loads.  No LDS, no barriers. ----
template <int CPL>
__global__ __launch_bounds__(256) void k_gemv_row(const float* __restrict__ W,
                                                  const float* __restrict__ x,
                                                  float* __restrict__ y) {
    int lane = threadIdx.x & 63;
    int row = (blockIdx.x * 256 + threadIdx.x) >> 6;
    const f4* Wr = (const f4*)W + (size_t)row * (CPL * 64) + lane;
    const f4* X = (const f4*)x + lane;
    f4 wv[CPL];
#pragma unroll
    for (int k = 0; k < CPL; k++) wv[k] = __builtin_nontemporal_load(Wr + k * 64);
    float acc = 0.f;
#pragma unroll
    for (int k = 0; k < CPL; k++) {
        f4 xx = X[k * 64];
        acc += wv[k].x * xx.x + wv[k].y * xx.y + wv[k].z * xx.z + wv[k].w * xx.w;
    }
    acc = wave_red_sum(acc);
    if (lane == 0) y[row] = acc;
}

// ---- fused GeGLU: 1 row per wave, 20 nt loads back-to-back ----
__global__ __launch_bounds__(256) void k_geglu(const float* __restrict__ Wg,
                                               const float* __restrict__ Wu,
                                               const float* __restrict__ h,
                                               float* __restrict__ gu) {
    int lane = threadIdx.x & 63;
    int row = (blockIdx.x * 256 + threadIdx.x) >> 6;
    const f4* G = (const f4*)Wg + (size_t)row * 640 + lane;
    const f4* U = (const f4*)Wu + (size_t)row * 640 + lane;
    const f4* X = (const f4*)h + lane;
    f4 wg[10], wu[10];
#pragma unroll
    for (int k = 0; k < 10; k++) wg[k] = __builtin_nontemporal_load(G + k * 64);
#pragma unroll
    for (int k = 0; k < 10; k++) wu[k] = __builtin_nontemporal_load(U + k * 64);
    float ag = 0.f, au = 0.f;
#pragma unroll
    for (int k = 0; k < 10; k++) {
        f4 xx = X[k * 64];
        ag += wg[k].x * xx.x + wg[k].y * xx.y + wg[k].z * xx.z + wg[k].w * xx.w;
        au += wu[k].x * xx.x + wu[k].y * xx.y + wu[k].z * xx.z + wu[k].w * xx.w;
    }
#pragma unroll
    for (int o = 32; o > 0; o >>= 1) {
        ag += __shfl_down(ag, o, 64);
        au += __shfl_down(au, o, 64);
    }
    if (lane == 0) {
        float g = ag;
        float tt = tanhf(0.7978845608028654f * (g + 0.044715f * g * g * g));
        gu[row] = 0.5f * g * (1.f + tt) * au;
    }
}

// ---- Wd: half-row per wave (20 nt loads), 2 partials/row ----
__global__ __launch_bounds__(256) void k_wd(const float* __restrict__ Wd,
                                            const float* __restrict__ gu,
                                            float* __restrict__ part) {
    int lane = threadIdx.x & 63;
    int t = (blockIdx.x * 256 + threadIdx.x) >> 6;   // task: row*2+half
    int half = t & 1;
    const f4* Wr = (const f4*)Wd + (size_t)t * 1280 + lane;
    const f4* X = (const f4*)gu + half * 1280 + lane;
    f4 wv[20];
#pragma unroll
    for (int k = 0; k < 20; k++) wv[k] = __builtin_nontemporal_load(Wr + k * 64);
    float acc = 0.f;
#pragma unroll
    for (int k = 0; k < 20; k++) {
        f4 xx = X[k * 64];
        acc += wv[k].x * xx.x + wv[k].y * xx.y + wv[k].z * xx.z + wv[k].w * xx.w;
    }
    acc = wave_red_sum(acc);
    if (lane == 0) part[t] = acc;
}

// out1 = (res?) res + rms(a)*(1+w1);  a[i] = sum_{s<slots} apart[i*slots+s]
// optionally out2 = rms(out1)*(1+w2).  one block, 256 threads.
__global__ void k_res_rms(const float* __restrict__ res,
                          const float* __restrict__ apart, int slots,
                          const float* __restrict__ w1, float* __restrict__ out1,
                          const float* __restrict__ w2, float* __restrict__ out2) {
    const int K = D_ / 256;
    int t = threadIdx.x;
    float va[K];
    float ss = 0.f;
#pragma unroll
    for (int k = 0; k < K; k++) {
        int i = t + k * 256;
        float v = 0.f;
        for (int s = 0; s < slots; s++) v += apart[(size_t)i * slots + s];
        va[k] = v;
        ss += v * v;
    }
    float tot = block_red_sum(ss);
    float rs = rsqrtf(tot / (float)D_ + EPSF);
    float vo[K];
    float ss2 = 0.f;
#pragma unroll
    for (int k = 0; k < K; k++) {
        int i = t + k * 256;
        float r = res ? res[i] : 0.f;
        vo[k] = r + va[k] * rs * (1.f + w1[i]);
        out1[i] = vo[k];
        ss2 += vo[k] * vo[k];
    }
    if (out2) {
        float tot2 = block_red_sum(ss2);
        float rs2 = rsqrtf(tot2 / (float)D_ + EPSF);
#pragma unroll
        for (int k = 0; k < K; k++) {
            int i = t + k * 256;
            out2[i] = vo[k] * rs2 * (1.f + w2[i]);
        }
    }
}

// ---- flash-decode partial: one block per (kvh, 64-row chunk).
// Fuses q-norm + RoPE (recomputed cheaply per block), scores+mask,
// local softmax, and PV accumulation.  Outputs (m, l, acc) per head/chunk.
__global__ __launch_bounds__(256) void k_attn_part(const float* __restrict__ Kc,
                                                   const float* __restrict__ V,
                                                   const float* __restrict__ qraw,
                                                   const float* __restrict__ cosv,
                                                   const float* __restrict__ sinv,
                                                   const float* __restrict__ mask,
                                                   float* __restrict__ pm,
                                                   float* __restrict__ pl,
                                                   float* __restrict__ pacc) {
    int kvh = blockIdx.x, ch = blockIdx.y;
    int lane = threadIdx.x & 63, w = threadIdx.x >> 6;
    int t = threadIdx.x;
    int h0 = 2 * kvh, h1 = h0 + 1;
    int l0 = ch * 64;
    __shared__ float s0[64], s1[64];

    // q-norm + rope, in-register (f4 per lane covers the 256-dim head)
    const f4* q4 = (const f4*)qraw;
    f4 qr0 = q4[h0 * 64 + lane];
    f4 qr1 = q4[h1 * 64 + lane];
    float n0 = wave_red_sum_b(qr0.x * qr0.x + qr0.y * qr0.y + qr0.z * qr0.z + qr0.w * qr0.w);
    float n1 = wave_red_sum_b(qr1.x * qr1.x + qr1.y * qr1.y + qr1.z * qr1.z + qr1.w * qr1.w);
    f4 qn0 = qr0 * rsqrtf(n0 / (float)HD_ + EPSF);
    f4 qn1 = qr1 * rsqrtf(n1 / (float)HD_ + EPSF);
    f4 p0, p1;
    p0.x = __shfl_xor(qn0.x, 32, 64); p0.y = __shfl_xor(qn0.y, 32, 64);
    p0.z = __shfl_xor(qn0.z, 32, 64); p0.w = __shfl_xor(qn0.w, 32, 64);
    p1.x = __shfl_xor(qn1.x, 32, 64); p1.y = __shfl_xor(qn1.y, 32, 64);
    p1.z = __shfl_xor(qn1.z, 32, 64); p1.w = __shfl_xor(qn1.w, 32, 64);
    f4 rot0 = (lane < 32) ? -p0 : p0;
    f4 rot1 = (lane < 32) ? -p1 : p1;
    f4 cs = ((const f4*)cosv)[lane];
    f4 sn = ((const f4*)sinv)[lane];
    f4 q0 = qn0 * cs + rot0 * sn;
    f4 q1 = qn1 * cs + rot1 * sn;

    // scores: wave w handles rows w*16 .. w*16+15 (16-deep K loads)
    const f4* Kb = (const f4*)Kc + ((size_t)kvh * CTX_ + l0 + w * 16) * 64 + lane;
    f4 kk[16];
#pragma unroll
    for (int i = 0; i < 16; i++) kk[i] = Kb[i * 64];
    float d0[16], d1[16];
#pragma unroll
    for (int i = 0; i < 16; i++) {
        d0[i] = kk[i].x * q0.x + kk[i].y * q0.y + kk[i].z * q0.z + kk[i].w * q0.w;
        d1[i] = kk[i].x * q1.x + kk[i].y * q1.y + kk[i].z * q1.z + kk[i].w * q1.w;
    }
#pragma unroll
    for (int o = 32; o > 0; o >>= 1) {
#pragma unroll
        for (int i = 0; i < 16; i++) {
            d0[i] += __shfl_down(d0[i], o, 64);
            d1[i] += __shfl_down(d1[i], o, 64);
        }
    }
    if (lane == 0) {
#pragma unroll
        for (int i = 0; i < 16; i++) {
            float m = mask[l0 + w * 16 + i];
            s0[w * 16 + i] = d0[i] + m;
            s1[w * 16 + i] = d1[i] + m;
        }
    }
    __syncthreads();

    // local softmax over the 64 rows
    float m0 = block_red_max(t < 64 ? s0[t] : -3e38f);
    float m1 = block_red_max(t < 64 ? s1[t] : -3e38f);
    float e0 = 0.f, e1 = 0.f;
    if (t < 64) {
        e0 = expf(s0[t] - m0); s0[t] = e0;
        e1 = expf(s1[t] - m1); s1[t] = e1;
    }
    float l0sum = block_red_sum(e0);
    float l1sum = block_red_sum(e1);

    // PV: thread = output dim d, stream 64 V rows (coalesced)
    const float* Vb = V + ((size_t)kvh * CTX_ + l0) * HD_ + t;
    float a0 = 0.f, a1 = 0.f;
#pragma unroll 8
    for (int li = 0; li < 64; li++) {
        float v = Vb[(size_t)li * HD_];
        a0 += s0[li] * v;
        a1 += s1[li] * v;
    }
    pacc[((size_t)(h0 * ACH) + ch) * HD_ + t] = a0;
    pacc[((size_t)(h1 * ACH) + ch) * HD_ + t] = a1;
    if (t == 0) {
        pm[h0 * ACH + ch] = m0; pl[h0 * ACH + ch] = l0sum;
        pm[h1 * ACH + ch] = m1; pl[h1 * ACH + ch] = l1sum;
    }
}

// ---- combine: grid = NH_, thread = d ----
__global__ __launch_bounds__(256) void k_attn_comb(const float* __restrict__ pm,
                                                   const float* __restrict__ pl,
                                                   const float* __restrict__ pacc,
                                                   float* __restrict__ a) {
    int h = blockIdx.x, t = threadIdx.x;
    __shared__ float wgt[ACH];
    float M = block_red_max(t < ACH ? pm[h * ACH + t] : -3e38f);
    float lw = 0.f;
    if (t < ACH) {
        float wv = expf(pm[h * ACH + t] - M);
        wgt[t] = wv;
        lw = wv * pl[h * ACH + t];
    }
    float L = block_red_sum(lw);
    float acc = 0.f;
    const float* pb = pacc + (size_t)h * ACH * HD_ + t;
#pragma unroll 8
    for (int c = 0; c < ACH; c++) acc += wgt[c] * pb[(size_t)c * HD_];
    a[h * HD_ + t] = acc / L;
}

extern "C" void kernel_launch(void* const* d_in, const int* in_sizes, int n_in,
                              void* d_out, int out_size, void* d_ws, size_t ws_size,
                              hipStream_t stream) {
    const float* x     = (const float*)d_in[0];
    const float* cosv  = (const float*)d_in[1];
    const float* sinv  = (const float*)d_in[2];
    const float* mask  = (const float*)d_in[3];
    const float* cK    = (const float*)d_in[4];
    const float* cV    = (const float*)d_in[5];
    const float* w_in  = (const float*)d_in[7];
    const float* w_pa  = (const float*)d_in[8];
    const float* w_pf  = (const float*)d_in[9];
    const float* w_pff = (const float*)d_in[10];
    const float* Wq    = (const float*)d_in[11];
    const float* Wo    = (const float*)d_in[12];
    const float* Wg    = (const float*)d_in[13];
    const float* Wu    = (const float*)d_in[14];
    const float* Wd    = (const float*)d_in[15];

    float* ws    = (float*)d_ws;
    float* h     = ws;             // 2560
    float* qraw  = ws + 2560;      // 2048
    float* pm    = ws + 4608;      // 512
    float* pl    = ws + 5120;      // 512
    float* pacc  = ws + 5632;      // 8*64*256 = 131072
    float* a     = ws + 136704;    // 2048
    float* ao    = ws + 138752;    // 2560
    float* x2    = ws + 141312;    // 2560
    float* h2    = ws + 143872;    // 2560
    float* gu    = ws + 146432;    // 10240
    float* partd = ws + 156672;    // 5120
    float* out   = (float*)d_out;

    // h = rmsnorm(x, w_in)
    k_res_rms<<<1, 256, 0, stream>>>(nullptr, x, 1, w_in, h, nullptr, nullptr);
    // qraw = h @ Wq.T  (2048 waves, 1 row each)
    k_gemv_row<10><<<QD_ / 4, 256, 0, stream>>>(Wq, h, qraw);
    // attention: flash-decode partials + combine (qnorm/rope fused)
    k_attn_part<<<dim3(NKV_, ACH), 256, 0, stream>>>(cK, cV, qraw, cosv, sinv,
                                                     mask, pm, pl, pacc);
    k_attn_comb<<<NH_, 256, 0, stream>>>(pm, pl, pacc, a);
    // ao = a @ Wo.T  (2560 waves)
    k_gemv_row<8><<<D_ / 4, 256, 0, stream>>>(Wo, a, ao);
    // x2 = x + rms(ao)*(1+w_pa);  h2 = rms(x2)*(1+w_pf)
    k_res_rms<<<1, 256, 0, stream>>>(x, ao, 1, w_pa, x2, w_pf, h2);
    // gu = gelu(h2@Wg.T) * (h2@Wu.T)  (10240 waves)
    k_geglu<<<FFN_ / 4, 256, 0, stream>>>(Wg, Wu, h2, gu);
    // ffn partials = gu @ Wd.T  (5120 waves, half-row each)
    k_wd<<<D_ * 2 / 4, 256, 0, stream>>>(Wd, gu, partd);
    // out = x2 + rms(sum partd)*(1+w_pff)
    k_res_rms<<<1, 256, 0, stream>>>(x2, partd, 2, w_pff, out, nullptr, nullptr);
}

// Round 10
// 91.346 us; speedup vs baseline: 1.2544x; 1.0902x over previous
//
#include <hip/hip_runtime.h>

#define D_    2560
#define NH_   8
#define NKV_  4
#define HD_   256
#define FFN_  10240
#define QD_   2048
#define CTX_  4096
#define EPSF  1e-6f
#define ACH   64    // attention chunks per kv head (64 rows each)

typedef float f4 __attribute__((ext_vector_type(4)));

__device__ __forceinline__ float wave_red_sum(float v) {
#pragma unroll
    for (int o = 32; o > 0; o >>= 1) v += __shfl_down(v, o, 64);
    return v;
}

// butterfly: result in ALL lanes
__device__ __forceinline__ float wave_red_sum_b(float v) {
#pragma unroll
    for (int o = 32; o > 0; o >>= 1) v += __shfl_xor(v, o, 64);
    return v;
}

template <int NW>
__device__ __forceinline__ float block_red_sum(float v) {
    __shared__ float s[NW];
    __shared__ float tot;
    int lane = threadIdx.x & 63, w = threadIdx.x >> 6;
    v = wave_red_sum(v);
    if (lane == 0) s[w] = v;
    __syncthreads();
    if (threadIdx.x == 0) {
        float t = 0.f;
#pragma unroll
        for (int i = 0; i < NW; i++) t += s[i];
        tot = t;
    }
    __syncthreads();
    return tot;
}

template <int NW>
__device__ __forceinline__ float block_red_max(float v) {
    __shared__ float s[NW];
    __shared__ float tot;
    int lane = threadIdx.x & 63, w = threadIdx.x >> 6;
#pragma unroll
    for (int o = 32; o > 0; o >>= 1) v = fmaxf(v, __shfl_down(v, o, 64));
    if (lane == 0) s[w] = v;
    __syncthreads();
    if (threadIdx.x == 0) {
        float t = -3e38f;
#pragma unroll
        for (int i = 0; i < NW; i++) t = fmaxf(t, s[i]);
        tot = t;
    }
    __syncthreads();
    return tot;
}

// ---- Wq GEMV with inline rmsnorm(x, w_in): qraw[row] = Wq[row,:] . (rms(x)*(1+w_in))
// 1 row/wave, 10 nt weight loads first, then cached x/w loads + butterfly rms.
__global__ __launch_bounds__(256) void k_wq_fused(const float* __restrict__ Wq,
                                                  const float* __restrict__ x,
                                                  const float* __restrict__ w_in,
                                                  float* __restrict__ qraw) {
    int lane = threadIdx.x & 63;
    int row = (blockIdx.x * 256 + threadIdx.x) >> 6;
    const f4* Wr = (const f4*)Wq + (size_t)row * 640 + lane;
    const f4* X = (const f4*)x + lane;
    const f4* WI = (const f4*)w_in + lane;
    f4 wv[10];
#pragma unroll
    for (int k = 0; k < 10; k++) wv[k] = __builtin_nontemporal_load(Wr + k * 64);
    f4 xx[10];
#pragma unroll
    for (int k = 0; k < 10; k++) xx[k] = X[k * 64];
    float ss = 0.f;
#pragma unroll
    for (int k = 0; k < 10; k++)
        ss += xx[k].x * xx[k].x + xx[k].y * xx[k].y + xx[k].z * xx[k].z + xx[k].w * xx[k].w;
    ss = wave_red_sum_b(ss);
    float rs = rsqrtf(ss / (float)D_ + EPSF);
    float acc = 0.f;
#pragma unroll
    for (int k = 0; k < 10; k++) {
        f4 wi = WI[k * 64];
        f4 hh = xx[k] * rs * (1.f + wi);
        acc += wv[k].x * hh.x + wv[k].y * hh.y + wv[k].z * hh.z + wv[k].w * hh.w;
    }
    acc = wave_red_sum(acc);
    if (lane == 0) qraw[row] = acc;
}

// ---- probe-shaped GEMV: 1 row per wave, CPL back-to-back nt loads ----
template <int CPL>
__global__ __launch_bounds__(256) void k_gemv_row(const float* __restrict__ W,
                                                  const float* __restrict__ x,
                                                  float* __restrict__ y) {
    int lane = threadIdx.x & 63;
    int row = (blockIdx.x * 256 + threadIdx.x) >> 6;
    const f4* Wr = (const f4*)W + (size_t)row * (CPL * 64) + lane;
    const f4* X = (const f4*)x + lane;
    f4 wv[CPL];
#pragma unroll
    for (int k = 0; k < CPL; k++) wv[k] = __builtin_nontemporal_load(Wr + k * 64);
    float acc = 0.f;
#pragma unroll
    for (int k = 0; k < CPL; k++) {
        f4 xx = X[k * 64];
        acc += wv[k].x * xx.x + wv[k].y * xx.y + wv[k].z * xx.z + wv[k].w * xx.w;
    }
    acc = wave_red_sum(acc);
    if (lane == 0) y[row] = acc;
}

// ---- fused GeGLU: 1 row per wave, 20 nt loads back-to-back ----
__global__ __launch_bounds__(256) void k_geglu(const float* __restrict__ Wg,
                                               const float* __restrict__ Wu,
                                               const float* __restrict__ h,
                                               float* __restrict__ gu) {
    int lane = threadIdx.x & 63;
    int row = (blockIdx.x * 256 + threadIdx.x) >> 6;
    const f4* G = (const f4*)Wg + (size_t)row * 640 + lane;
    const f4* U = (const f4*)Wu + (size_t)row * 640 + lane;
    const f4* X = (const f4*)h + lane;
    f4 wg[10], wu[10];
#pragma unroll
    for (int k = 0; k < 10; k++) wg[k] = __builtin_nontemporal_load(G + k * 64);
#pragma unroll
    for (int k = 0; k < 10; k++) wu[k] = __builtin_nontemporal_load(U + k * 64);
    float ag = 0.f, au = 0.f;
#pragma unroll
    for (int k = 0; k < 10; k++) {
        f4 xx = X[k * 64];
        ag += wg[k].x * xx.x + wg[k].y * xx.y + wg[k].z * xx.z + wg[k].w * xx.w;
        au += wu[k].x * xx.x + wu[k].y * xx.y + wu[k].z * xx.z + wu[k].w * xx.w;
    }
#pragma unroll
    for (int o = 32; o > 0; o >>= 1) {
        ag += __shfl_down(ag, o, 64);
        au += __shfl_down(au, o, 64);
    }
    if (lane == 0) {
        float g = ag;
        float tt = tanhf(0.7978845608028654f * (g + 0.044715f * g * g * g));
        gu[row] = 0.5f * g * (1.f + tt) * au;
    }
}

// ---- Wd: half-row per wave (20 nt loads), 2 partials/row ----
__global__ __launch_bounds__(256) void k_wd(const float* __restrict__ Wd,
                                            const float* __restrict__ gu,
                                            float* __restrict__ part) {
    int lane = threadIdx.x & 63;
    int t = (blockIdx.x * 256 + threadIdx.x) >> 6;   // task: row*2+half
    int half = t & 1;
    const f4* Wr = (const f4*)Wd + (size_t)t * 1280 + lane;
    const f4* X = (const f4*)gu + half * 1280 + lane;
    f4 wv[20];
#pragma unroll
    for (int k = 0; k < 20; k++) wv[k] = __builtin_nontemporal_load(Wr + k * 64);
    float acc = 0.f;
#pragma unroll
    for (int k = 0; k < 20; k++) {
        f4 xx = X[k * 64];
        acc += wv[k].x * xx.x + wv[k].y * xx.y + wv[k].z * xx.z + wv[k].w * xx.w;
    }
    acc = wave_red_sum(acc);
    if (lane == 0) part[t] = acc;
}

// out1 = (res?) res + rms(a)*(1+w1);  a[i] = sum_{s<slots} apart[i*slots+s]
// optionally out2 = rms(out1)*(1+w2).  one block, 512 threads.
__global__ __launch_bounds__(512) void k_res_rms(const float* __restrict__ res,
                                                 const float* __restrict__ apart, int slots,
                                                 const float* __restrict__ w1, float* __restrict__ out1,
                                                 const float* __restrict__ w2, float* __restrict__ out2) {
    const int K = D_ / 512;
    int t = threadIdx.x;
    float va[K];
    float ss = 0.f;
#pragma unroll
    for (int k = 0; k < K; k++) {
        int i = t + k * 512;
        float v = 0.f;
        for (int s = 0; s < slots; s++) v += apart[(size_t)i * slots + s];
        va[k] = v;
        ss += v * v;
    }
    float tot = block_red_sum<8>(ss);
    float rs = rsqrtf(tot / (float)D_ + EPSF);
    float vo[K];
    float ss2 = 0.f;
#pragma unroll
    for (int k = 0; k < K; k++) {
        int i = t + k * 512;
        float r = res ? res[i] : 0.f;
        vo[k] = r + va[k] * rs * (1.f + w1[i]);
        out1[i] = vo[k];
        ss2 += vo[k] * vo[k];
    }
    if (out2) {
        float tot2 = block_red_sum<8>(ss2);
        float rs2 = rsqrtf(tot2 / (float)D_ + EPSF);
#pragma unroll
        for (int k = 0; k < K; k++) {
            int i = t + k * 512;
            out2[i] = vo[k] * rs2 * (1.f + w2[i]);
        }
    }
}

// ---- flash-decode partial: one block per (kvh, 64-row chunk).
// Fuses q-norm + RoPE, scores+mask, local softmax, PV (f4-vectorized).
__global__ __launch_bounds__(256) void k_attn_part(const float* __restrict__ Kc,
                                                   const float* __restrict__ V,
                                                   const float* __restrict__ qraw,
                                                   const float* __restrict__ cosv,
                                                   const float* __restrict__ sinv,
                                                   const float* __restrict__ mask,
                                                   float* __restrict__ pm,
                                                   float* __restrict__ pl,
                                                   float* __restrict__ pacc) {
    int kvh = blockIdx.x, ch = blockIdx.y;
    int lane = threadIdx.x & 63, w = threadIdx.x >> 6;
    int t = threadIdx.x;
    int h0 = 2 * kvh, h1 = h0 + 1;
    int l0 = ch * 64;
    __shared__ float s0[64], s1[64];
    __shared__ f4 pv0[4][64], pv1[4][64];

    // q-norm + rope, in-register (f4 per lane covers the 256-dim head)
    const f4* q4 = (const f4*)qraw;
    f4 qr0 = q4[h0 * 64 + lane];
    f4 qr1 = q4[h1 * 64 + lane];
    float n0 = wave_red_sum_b(qr0.x * qr0.x + qr0.y * qr0.y + qr0.z * qr0.z + qr0.w * qr0.w);
    float n1 = wave_red_sum_b(qr1.x * qr1.x + qr1.y * qr1.y + qr1.z * qr1.z + qr1.w * qr1.w);
    f4 qn0 = qr0 * rsqrtf(n0 / (float)HD_ + EPSF);
    f4 qn1 = qr1 * rsqrtf(n1 / (float)HD_ + EPSF);
    f4 p0, p1;
    p0.x = __shfl_xor(qn0.x, 32, 64); p0.y = __shfl_xor(qn0.y, 32, 64);
    p0.z = __shfl_xor(qn0.z, 32, 64); p0.w = __shfl_xor(qn0.w, 32, 64);
    p1.x = __shfl_xor(qn1.x, 32, 64); p1.y = __shfl_xor(qn1.y, 32, 64);
    p1.z = __shfl_xor(qn1.z, 32, 64); p1.w = __shfl_xor(qn1.w, 32, 64);
    f4 rot0 = (lane < 32) ? -p0 : p0;
    f4 rot1 = (lane < 32) ? -p1 : p1;
    f4 cs = ((const f4*)cosv)[lane];
    f4 sn = ((const f4*)sinv)[lane];
    f4 q0 = qn0 * cs + rot0 * sn;
    f4 q1 = qn1 * cs + rot1 * sn;

    // scores: wave w handles rows w*16 .. w*16+15 (16-deep K loads)
    const f4* Kb = (const f4*)Kc + ((size_t)kvh * CTX_ + l0 + w * 16) * 64 + lane;
    f4 kk[16];
#pragma unroll
    for (int i = 0; i < 16; i++) kk[i] = Kb[i * 64];
    float d0[16], d1[16];
#pragma unroll
    for (int i = 0; i < 16; i++) {
        d0[i] = kk[i].x * q0.x + kk[i].y * q0.y + kk[i].z * q0.z + kk[i].w * q0.w;
        d1[i] = kk[i].x * q1.x + kk[i].y * q1.y + kk[i].z * q1.z + kk[i].w * q1.w;
    }
#pragma unroll
    for (int o = 32; o > 0; o >>= 1) {
#pragma unroll
        for (int i = 0; i < 16; i++) {
            d0[i] += __shfl_down(d0[i], o, 64);
            d1[i] += __shfl_down(d1[i], o, 64);
        }
    }
    if (lane == 0) {
#pragma unroll
        for (int i = 0; i < 16; i++) {
            float m = mask[l0 + w * 16 + i];
            s0[w * 16 + i] = d0[i] + m;
            s1[w * 16 + i] = d1[i] + m;
        }
    }
    __syncthreads();

    // local softmax over the 64 rows
    float m0 = block_red_max<4>(t < 64 ? s0[t] : -3e38f);
    float m1 = block_red_max<4>(t < 64 ? s1[t] : -3e38f);
    float e0 = 0.f, e1 = 0.f;
    if (t < 64) {
        e0 = expf(s0[t] - m0); s0[t] = e0;
        e1 = expf(s1[t] - m1); s1[t] = e1;
    }
    float l0sum = block_red_sum<4>(e0);
    float l1sum = block_red_sum<4>(e1);

    // PV: wave w covers rows [w*16, w*16+16), f4 per lane (16-deep loads)
    const f4* Vb = (const f4*)V + ((size_t)kvh * CTX_ + l0 + w * 16) * 64 + lane;
    f4 vv[16];
#pragma unroll
    for (int i = 0; i < 16; i++) vv[i] = Vb[i * 64];
    f4 a0 = {0.f, 0.f, 0.f, 0.f}, a1 = {0.f, 0.f, 0.f, 0.f};
#pragma unroll
    for (int i = 0; i < 16; i++) {
        a0 += vv[i] * s0[w * 16 + i];
        a1 += vv[i] * s1[w * 16 + i];
    }
    pv0[w][lane] = a0;
    pv1[w][lane] = a1;
    __syncthreads();
    // combine 4 wave partials: thread t owns dim t
    const float* f0 = (const float*)pv0;
    const float* f1 = (const float*)pv1;
    float r0 = f0[t] + f0[256 + t] + f0[512 + t] + f0[768 + t];
    float r1 = f1[t] + f1[256 + t] + f1[512 + t] + f1[768 + t];
    pacc[((size_t)(h0 * ACH) + ch) * HD_ + t] = r0;
    pacc[((size_t)(h1 * ACH) + ch) * HD_ + t] = r1;
    if (t == 0) {
        pm[h0 * ACH + ch] = m0; pl[h0 * ACH + ch] = l0sum;
        pm[h1 * ACH + ch] = m1; pl[h1 * ACH + ch] = l1sum;
    }
}

// ---- combine: grid = NH_, thread = d ----
__global__ __launch_bounds__(256) void k_attn_comb(const float* __restrict__ pm,
                                                   const float* __restrict__ pl,
                                                   const float* __restrict__ pacc,
                                                   float* __restrict__ a) {
    int h = blockIdx.x, t = threadIdx.x;
    __shared__ float wgt[ACH];
    float M = block_red_max<4>(t < ACH ? pm[h * ACH + t] : -3e38f);
    float lw = 0.f;
    if (t < ACH) {
        float wv = expf(pm[h * ACH + t] - M);
        wgt[t] = wv;
        lw = wv * pl[h * ACH + t];
    }
    float L = block_red_sum<4>(lw);
    float acc = 0.f;
    const float* pb = pacc + (size_t)h * ACH * HD_ + t;
#pragma unroll 8
    for (int c = 0; c < ACH; c++) acc += wgt[c] * pb[(size_t)c * HD_];
    a[h * HD_ + t] = acc / L;
}

extern "C" void kernel_launch(void* const* d_in, const int* in_sizes, int n_in,
                              void* d_out, int out_size, void* d_ws, size_t ws_size,
                              hipStream_t stream) {
    const float* x     = (const float*)d_in[0];
    const float* cosv  = (const float*)d_in[1];
    const float* sinv  = (const float*)d_in[2];
    const float* mask  = (const float*)d_in[3];
    const float* cK    = (const float*)d_in[4];
    const float* cV    = (const float*)d_in[5];
    const float* w_in  = (const float*)d_in[7];
    const float* w_pa  = (const float*)d_in[8];
    const float* w_pf  = (const float*)d_in[9];
    const float* w_pff = (const float*)d_in[10];
    const float* Wq    = (const float*)d_in[11];
    const float* Wo    = (const float*)d_in[12];
    const float* Wg    = (const float*)d_in[13];
    const float* Wu    = (const float*)d_in[14];
    const float* Wd    = (const float*)d_in[15];

    float* ws    = (float*)d_ws;
    float* qraw  = ws;             // 2048
    float* pm    = ws + 2048;      // 512
    float* pl    = ws + 2560;      // 512
    float* pacc  = ws + 3072;      // 131072
    float* a     = ws + 134144;    // 2048
    float* ao    = ws + 136192;    // 2560
    float* x2    = ws + 138752;    // 2560
    float* h2    = ws + 141312;    // 2560
    float* gu    = ws + 143872;    // 10240
    float* partd = ws + 154112;    // 5120
    float* out   = (float*)d_out;

    // qraw = rmsnorm(x,w_in) @ Wq.T  (fused, 2048 waves)
    k_wq_fused<<<QD_ / 4, 256, 0, stream>>>(Wq, x, w_in, qraw);
    // attention: flash-decode partials + combine (qnorm/rope fused)
    k_attn_part<<<dim3(NKV_, ACH), 256, 0, stream>>>(cK, cV, qraw, cosv, sinv,
                                                     mask, pm, pl, pacc);
    k_attn_comb<<<NH_, 256, 0, stream>>>(pm, pl, pacc, a);
    // ao = a @ Wo.T  (2560 waves)
    k_gemv_row<8><<<D_ / 4, 256, 0, stream>>>(Wo, a, ao);
    // x2 = x + rms(ao)*(1+w_pa);  h2 = rms(x2)*(1+w_pf)
    k_res_rms<<<1, 512, 0, stream>>>(x, ao, 1, w_pa, x2, w_pf, h2);
    // gu = gelu(h2@Wg.T) * (h2@Wu.T)  (10240 waves)
    k_geglu<<<FFN_ / 4, 256, 0, stream>>>(Wg, Wu, h2, gu);
    // ffn partials = gu @ Wd.T  (5120 waves, half-row each)
    k_wd<<<D_ * 2 / 4, 256, 0, stream>>>(Wd, gu, partd);
    // out = x2 + rms(sum partd)*(1+w_pff)
    k_res_rms<<<1, 512, 0, stream>>>(x2, partd, 2, w_pff, out, nullptr, nullptr);
}

// Round 11
// 89.671 us; speedup vs baseline: 1.2778x; 1.0187x over previous
//
#include <hip/hip_runtime.h>

#define D_    2560
#define NH_   8
#define NKV_  4
#define HD_   256
#define FFN_  10240
#define QD_   2048
#define CTX_  4096
#define EPSF  1e-6f
#define ACH   128   // attention chunks per kv head (32 rows each)

typedef float f4 __attribute__((ext_vector_type(4)));

__device__ __forceinline__ float wave_red_sum(float v) {
#pragma unroll
    for (int o = 32; o > 0; o >>= 1) v += __shfl_down(v, o, 64);
    return v;
}

// butterfly: result in ALL lanes
__device__ __forceinline__ float wave_red_sum_b(float v) {
#pragma unroll
    for (int o = 32; o > 0; o >>= 1) v += __shfl_xor(v, o, 64);
    return v;
}

template <int NW>
__device__ __forceinline__ float block_red_sum(float v) {
    __shared__ float s[NW];
    __shared__ float tot;
    int lane = threadIdx.x & 63, w = threadIdx.x >> 6;
    v = wave_red_sum(v);
    if (lane == 0) s[w] = v;
    __syncthreads();
    if (threadIdx.x == 0) {
        float t = 0.f;
#pragma unroll
        for (int i = 0; i < NW; i++) t += s[i];
        tot = t;
    }
    __syncthreads();
    return tot;
}

template <int NW>
__device__ __forceinline__ float block_red_max(float v) {
    __shared__ float s[NW];
    __shared__ float tot;
    int lane = threadIdx.x & 63, w = threadIdx.x >> 6;
#pragma unroll
    for (int o = 32; o > 0; o >>= 1) v = fmaxf(v, __shfl_down(v, o, 64));
    if (lane == 0) s[w] = v;
    __syncthreads();
    if (threadIdx.x == 0) {
        float t = -3e38f;
#pragma unroll
        for (int i = 0; i < NW; i++) t = fmaxf(t, s[i]);
        tot = t;
    }
    __syncthreads();
    return tot;
}

// ---- Wq GEMV with inline rmsnorm(x, w_in).  x/w_in loads issued BEFORE the
// W burst; wv consumed in issue order (incremental vmcnt waits). ----
__global__ __launch_bounds__(256) void k_wq_fused(const float* __restrict__ Wq,
                                                  const float* __restrict__ x,
                                                  const float* __restrict__ w_in,
                                                  float* __restrict__ qraw) {
    int lane = threadIdx.x & 63;
    int row = (blockIdx.x * 256 + threadIdx.x) >> 6;
    const f4* X = (const f4*)x + lane;
    const f4* WI = (const f4*)w_in + lane;
    f4 xx[10], wi[10];
#pragma unroll
    for (int k = 0; k < 10; k++) xx[k] = X[k * 64];
#pragma unroll
    for (int k = 0; k < 10; k++) wi[k] = WI[k * 64];
    const f4* Wr = (const f4*)Wq + (size_t)row * 640 + lane;
    f4 wv[10];
#pragma unroll
    for (int k = 0; k < 10; k++) wv[k] = __builtin_nontemporal_load(Wr + k * 64);
    float ss = 0.f;
#pragma unroll
    for (int k = 0; k < 10; k++)
        ss += xx[k].x * xx[k].x + xx[k].y * xx[k].y + xx[k].z * xx[k].z + xx[k].w * xx[k].w;
    ss = wave_red_sum_b(ss);
    float rs = rsqrtf(ss / (float)D_ + EPSF);
    float acc = 0.f;
#pragma unroll
    for (int k = 0; k < 10; k++) {
        f4 hh = xx[k] * rs * (1.f + wi[k]);
        acc += wv[k].x * hh.x + wv[k].y * hh.y + wv[k].z * hh.z + wv[k].w * hh.w;
    }
    acc = wave_red_sum(acc);
    if (lane == 0) qraw[row] = acc;
}

// ---- GEMV: x preloaded before W burst, in-order consumption ----
template <int CPL>
__global__ __launch_bounds__(256) void k_gemv_row(const float* __restrict__ W,
                                                  const float* __restrict__ x,
                                                  float* __restrict__ y) {
    int lane = threadIdx.x & 63;
    int row = (blockIdx.x * 256 + threadIdx.x) >> 6;
    const f4* X = (const f4*)x + lane;
    f4 xx[CPL];
#pragma unroll
    for (int k = 0; k < CPL; k++) xx[k] = X[k * 64];
    const f4* Wr = (const f4*)W + (size_t)row * (CPL * 64) + lane;
    f4 wv[CPL];
#pragma unroll
    for (int k = 0; k < CPL; k++) wv[k] = __builtin_nontemporal_load(Wr + k * 64);
    float acc = 0.f;
#pragma unroll
    for (int k = 0; k < CPL; k++)
        acc += wv[k].x * xx[k].x + wv[k].y * xx[k].y + wv[k].z * xx[k].z + wv[k].w * xx[k].w;
    acc = wave_red_sum(acc);
    if (lane == 0) y[row] = acc;
}

// ---- fused GeGLU — A/B EXPERIMENT: PLAIN (cached) weight loads this round.
// x preloaded first; weights consumed in issue order. ----
__global__ __launch_bounds__(256) void k_geglu(const float* __restrict__ Wg,
                                               const float* __restrict__ Wu,
                                               const float* __restrict__ h,
                                               float* __restrict__ gu) {
    int lane = threadIdx.x & 63;
    int row = (blockIdx.x * 256 + threadIdx.x) >> 6;
    const f4* X = (const f4*)h + lane;
    f4 xx[10];
#pragma unroll
    for (int k = 0; k < 10; k++) xx[k] = X[k * 64];
    const f4* G = (const f4*)Wg + (size_t)row * 640 + lane;
    const f4* U = (const f4*)Wu + (size_t)row * 640 + lane;
    f4 wg[10], wu[10];
#pragma unroll
    for (int k = 0; k < 10; k++) wg[k] = G[k * 64];
#pragma unroll
    for (int k = 0; k < 10; k++) wu[k] = U[k * 64];
    float ag = 0.f, au = 0.f;
#pragma unroll
    for (int k = 0; k < 10; k++)
        ag += wg[k].x * xx[k].x + wg[k].y * xx[k].y + wg[k].z * xx[k].z + wg[k].w * xx[k].w;
#pragma unroll
    for (int k = 0; k < 10; k++)
        au += wu[k].x * xx[k].x + wu[k].y * xx[k].y + wu[k].z * xx[k].z + wu[k].w * xx[k].w;
#pragma unroll
    for (int o = 32; o > 0; o >>= 1) {
        ag += __shfl_down(ag, o, 64);
        au += __shfl_down(au, o, 64);
    }
    if (lane == 0) {
        float g = ag;
        float tt = tanhf(0.7978845608028654f * (g + 0.044715f * g * g * g));
        gu[row] = 0.5f * g * (1.f + tt) * au;
    }
}

// ---- Wd: half-row per wave, nt weights, 2 batches of {x preload, W burst} ----
__global__ __launch_bounds__(256) void k_wd(const float* __restrict__ Wd,
                                            const float* __restrict__ gu,
                                            float* __restrict__ part) {
    int lane = threadIdx.x & 63;
    int t = (blockIdx.x * 256 + threadIdx.x) >> 6;   // task: row*2+half
    int half = t & 1;
    const f4* Wr = (const f4*)Wd + (size_t)t * 1280 + lane;
    const f4* Xp = (const f4*)gu + half * 1280 + lane;
    float acc = 0.f;
#pragma unroll
    for (int b = 0; b < 2; b++) {
        f4 xx[10], wv[10];
#pragma unroll
        for (int j = 0; j < 10; j++) xx[j] = Xp[(b * 10 + j) * 64];
#pragma unroll
        for (int j = 0; j < 10; j++)
            wv[j] = __builtin_nontemporal_load(Wr + (b * 10 + j) * 64);
#pragma unroll
        for (int j = 0; j < 10; j++)
            acc += wv[j].x * xx[j].x + wv[j].y * xx[j].y + wv[j].z * xx[j].z + wv[j].w * xx[j].w;
    }
    acc = wave_red_sum(acc);
    if (lane == 0) part[t] = acc;
}

// out1 = (res?) res + rms(a)*(1+w1);  a[i] = sum_{s<slots} apart[i*slots+s]
// optionally out2 = rms(out1)*(1+w2).  one block, 512 threads.
__global__ __launch_bounds__(512) void k_res_rms(const float* __restrict__ res,
                                                 const float* __restrict__ apart, int slots,
                                                 const float* __restrict__ w1, float* __restrict__ out1,
                                                 const float* __restrict__ w2, float* __restrict__ out2) {
    const int K = D_ / 512;
    int t = threadIdx.x;
    float va[K];
    float ss = 0.f;
#pragma unroll
    for (int k = 0; k < K; k++) {
        int i = t + k * 512;
        float v = 0.f;
        for (int s = 0; s < slots; s++) v += apart[(size_t)i * slots + s];
        va[k] = v;
        ss += v * v;
    }
    float tot = block_red_sum<8>(ss);
    float rs = rsqrtf(tot / (float)D_ + EPSF);
    float vo[K];
    float ss2 = 0.f;
#pragma unroll
    for (int k = 0; k < K; k++) {
        int i = t + k * 512;
        float r = res ? res[i] : 0.f;
        vo[k] = r + va[k] * rs * (1.f + w1[i]);
        out1[i] = vo[k];
        ss2 += vo[k] * vo[k];
    }
    if (out2) {
        float tot2 = block_red_sum<8>(ss2);
        float rs2 = rsqrtf(tot2 / (float)D_ + EPSF);
#pragma unroll
        for (int k = 0; k < K; k++) {
            int i = t + k * 512;
            out2[i] = vo[k] * rs2 * (1.f + w2[i]);
        }
    }
}

// ---- flash-decode partial: one block per (kvh, 32-row chunk).  512 blocks.
__global__ __launch_bounds__(256) void k_attn_part(const float* __restrict__ Kc,
                                                   const float* __restrict__ V,
                                                   const float* __restrict__ qraw,
                                                   const float* __restrict__ cosv,
                                                   const float* __restrict__ sinv,
                                                   const float* __restrict__ mask,
                                                   float* __restrict__ pm,
                                                   float* __restrict__ pl,
                                                   float* __restrict__ pacc) {
    constexpr int RW = CTX_ / ACH;   // 32 rows per chunk, 8 per wave
    int kvh = blockIdx.x, ch = blockIdx.y;
    int lane = threadIdx.x & 63, w = threadIdx.x >> 6;
    int t = threadIdx.x;
    int h0 = 2 * kvh, h1 = h0 + 1;
    int l0 = ch * RW;
    __shared__ float s0[RW], s1[RW];
    __shared__ f4 pv0[4][64], pv1[4][64];

    // q-norm + rope, in-register
    const f4* q4 = (const f4*)qraw;
    f4 qr0 = q4[h0 * 64 + lane];
    f4 qr1 = q4[h1 * 64 + lane];
    float n0 = wave_red_sum_b(qr0.x * qr0.x + qr0.y * qr0.y + qr0.z * qr0.z + qr0.w * qr0.w);
    float n1 = wave_red_sum_b(qr1.x * qr1.x + qr1.y * qr1.y + qr1.z * qr1.z + qr1.w * qr1.w);
    f4 qn0 = qr0 * rsqrtf(n0 / (float)HD_ + EPSF);
    f4 qn1 = qr1 * rsqrtf(n1 / (float)HD_ + EPSF);
    f4 p0, p1;
    p0.x = __shfl_xor(qn0.x, 32, 64); p0.y = __shfl_xor(qn0.y, 32, 64);
    p0.z = __shfl_xor(qn0.z, 32, 64); p0.w = __shfl_xor(qn0.w, 32, 64);
    p1.x = __shfl_xor(qn1.x, 32, 64); p1.y = __shfl_xor(qn1.y, 32, 64);
    p1.z = __shfl_xor(qn1.z, 32, 64); p1.w = __shfl_xor(qn1.w, 32, 64);
    f4 rot0 = (lane < 32) ? -p0 : p0;
    f4 rot1 = (lane < 32) ? -p1 : p1;
    f4 cs = ((const f4*)cosv)[lane];
    f4 sn = ((const f4*)sinv)[lane];
    f4 q0 = qn0 * cs + rot0 * sn;
    f4 q1 = qn1 * cs + rot1 * sn;

    // scores: wave w handles rows w*8 .. w*8+7
    const f4* Kb = (const f4*)Kc + ((size_t)kvh * CTX_ + l0 + w * 8) * 64 + lane;
    f4 kk[8];
#pragma unroll
    for (int i = 0; i < 8; i++) kk[i] = Kb[i * 64];
    float d0[8], d1[8];
#pragma unroll
    for (int i = 0; i < 8; i++) {
        d0[i] = kk[i].x * q0.x + kk[i].y * q0.y + kk[i].z * q0.z + kk[i].w * q0.w;
        d1[i] = kk[i].x * q1.x + kk[i].y * q1.y + kk[i].z * q1.z + kk[i].w * q1.w;
    }
#pragma unroll
    for (int o = 32; o > 0; o >>= 1) {
#pragma unroll
        for (int i = 0; i < 8; i++) {
            d0[i] += __shfl_down(d0[i], o, 64);
            d1[i] += __shfl_down(d1[i], o, 64);
        }
    }
    if (lane == 0) {
#pragma unroll
        for (int i = 0; i < 8; i++) {
            float m = mask[l0 + w * 8 + i];
            s0[w * 8 + i] = d0[i] + m;
            s1[w * 8 + i] = d1[i] + m;
        }
    }
    __syncthreads();

    // local softmax over the 32 rows
    float m0 = block_red_max<4>(t < RW ? s0[t] : -3e38f);
    float m1 = block_red_max<4>(t < RW ? s1[t] : -3e38f);
    float e0 = 0.f, e1 = 0.f;
    if (t < RW) {
        e0 = expf(s0[t] - m0); s0[t] = e0;
        e1 = expf(s1[t] - m1); s1[t] = e1;
    }
    float l0sum = block_red_sum<4>(e0);
    float l1sum = block_red_sum<4>(e1);

    // PV: wave w covers rows [w*8, w*8+8), f4 per lane
    const f4* Vb = (const f4*)V + ((size_t)kvh * CTX_ + l0 + w * 8) * 64 + lane;
    f4 vv[8];
#pragma unroll
    for (int i = 0; i < 8; i++) vv[i] = Vb[i * 64];
    f4 a0 = {0.f, 0.f, 0.f, 0.f}, a1 = {0.f, 0.f, 0.f, 0.f};
#pragma unroll
    for (int i = 0; i < 8; i++) {
        a0 += vv[i] * s0[w * 8 + i];
        a1 += vv[i] * s1[w * 8 + i];
    }
    pv0[w][lane] = a0;
    pv1[w][lane] = a1;
    __syncthreads();
    const float* f0 = (const float*)pv0;
    const float* f1 = (const float*)pv1;
    float r0 = f0[t] + f0[256 + t] + f0[512 + t] + f0[768 + t];
    float r1 = f1[t] + f1[256 + t] + f1[512 + t] + f1[768 + t];
    pacc[((size_t)(h0 * ACH) + ch) * HD_ + t] = r0;
    pacc[((size_t)(h1 * ACH) + ch) * HD_ + t] = r1;
    if (t == 0) {
        pm[h0 * ACH + ch] = m0; pl[h0 * ACH + ch] = l0sum;
        pm[h1 * ACH + ch] = m1; pl[h1 * ACH + ch] = l1sum;
    }
}

// ---- combine: grid = NH_, thread = d ----
__global__ __launch_bounds__(256) void k_attn_comb(const float* __restrict__ pm,
                                                   const float* __restrict__ pl,
                                                   const float* __restrict__ pacc,
                                                   float* __restrict__ a) {
    int h = blockIdx.x, t = threadIdx.x;
    __shared__ float wgt[ACH];
    float M = block_red_max<4>(t < ACH ? pm[h * ACH + t] : -3e38f);
    float lw = 0.f;
    if (t < ACH) {
        float wv = expf(pm[h * ACH + t] - M);
        wgt[t] = wv;
        lw = wv * pl[h * ACH + t];
    }
    float L = block_red_sum<4>(lw);
    float acc = 0.f;
    const float* pb = pacc + (size_t)h * ACH * HD_ + t;
#pragma unroll 8
    for (int c = 0; c < ACH; c++) acc += wgt[c] * pb[(size_t)c * HD_];
    a[h * HD_ + t] = acc / L;
}

extern "C" void kernel_launch(void* const* d_in, const int* in_sizes, int n_in,
                              void* d_out, int out_size, void* d_ws, size_t ws_size,
                              hipStream_t stream) {
    const float* x     = (const float*)d_in[0];
    const float* cosv  = (const float*)d_in[1];
    const float* sinv  = (const float*)d_in[2];
    const float* mask  = (const float*)d_in[3];
    const float* cK    = (const float*)d_in[4];
    const float* cV    = (const float*)d_in[5];
    const float* w_in  = (const float*)d_in[7];
    const float* w_pa  = (const float*)d_in[8];
    const float* w_pf  = (const float*)d_in[9];
    const float* w_pff = (const float*)d_in[10];
    const float* Wq    = (const float*)d_in[11];
    const float* Wo    = (const float*)d_in[12];
    const float* Wg    = (const float*)d_in[13];
    const float* Wu    = (const float*)d_in[14];
    const float* Wd    = (const float*)d_in[15];

    float* ws    = (float*)d_ws;
    float* qraw  = ws;             // 2048
    float* pm    = ws + 2048;      // 1024
    float* pl    = ws + 3072;      // 1024
    float* pacc  = ws + 4096;      // 8*128*256 = 262144
    float* a     = ws + 266240;    // 2048
    float* ao    = ws + 268288;    // 2560
    float* x2    = ws + 270848;    // 2560
    float* h2    = ws + 273408;    // 2560
    float* gu    = ws + 275968;    // 10240
    float* partd = ws + 286208;    // 5120
    float* out   = (float*)d_out;

    // qraw = rmsnorm(x,w_in) @ Wq.T  (fused)
    k_wq_fused<<<QD_ / 4, 256, 0, stream>>>(Wq, x, w_in, qraw);
    // attention: flash-decode partials + combine
    k_attn_part<<<dim3(NKV_, ACH), 256, 0, stream>>>(cK, cV, qraw, cosv, sinv,
                                                     mask, pm, pl, pacc);
    k_attn_comb<<<NH_, 256, 0, stream>>>(pm, pl, pacc, a);
    // ao = a @ Wo.T
    k_gemv_row<8><<<D_ / 4, 256, 0, stream>>>(Wo, a, ao);
    // x2 = x + rms(ao)*(1+w_pa);  h2 = rms(x2)*(1+w_pf)
    k_res_rms<<<1, 512, 0, stream>>>(x, ao, 1, w_pa, x2, w_pf, h2);
    // gu = gelu(h2@Wg.T) * (h2@Wu.T)   [plain loads this round — A/B vs nt]
    k_geglu<<<FFN_ / 4, 256, 0, stream>>>(Wg, Wu, h2, gu);
    // ffn partials = gu @ Wd.T  [nt kept]
    k_wd<<<D_ * 2 / 4, 256, 0, stream>>>(Wd, gu, partd);
    // out = x2 + rms(sum partd)*(1+w_pff)
    k_res_rms<<<1, 512, 0, stream>>>(x2, partd, 2, w_pff, out, nullptr, nullptr);
}